// Round 10
// baseline (302.374 us; speedup 1.0000x reference)
//
#include <hip/hip_runtime.h>
#include <stdint.h>
#include <math.h>

// FuXi block on MI355X, round 19: 8-phase 256x256 GEMM for QKVU (guide m201 port).
// r18 post-mortem: coarse 2-phase counted-vmcnt NULL (297.8->299.4) -- consistent
// with m196/m233 regime gate: only the fine 8-phase interleave amortizes the stage
// stall. gemm64/gemm_w1 reverted to r17. QKVU GEMM -> 256^2 tile, 8 waves (2Mx4N),
// BK=64, 2 K-tiles/iter, 8 phases x 16 MFMA, stage 1 half-tile/phase (2 glds),
// vmcnt(4) ONLY before phases 1 and 5 (bookkeeping: 12 outstanding -> completes the
// K-tile about to be read, leaves 4). Stage plan ph1,2=t1-A ph3,4=t2-B ph5,6=t2-A
// ph7,8=t3-B (each slot staged >=1 phase after its last reader, vmcnt-gated 4 phases
// before its first reader). Prologue 6 half-tiles; tail drains vmcnt(0) at phase 5.
// LDS 128KB, grid 256 = 1 block/CU. attn unchanged (control).

#define D    1024
#define NH   16
#define DH   64
#define B_   2
#define S_   2048
#define ROWS 4096
#define LQ   4096          // QKVU row stride
#define EPSR 1e-8f

typedef unsigned short u16;
typedef __attribute__((ext_vector_type(8))) short short8;
typedef __attribute__((ext_vector_type(4))) float f32x4;
typedef __attribute__((ext_vector_type(16))) float f32x16;
typedef __attribute__((ext_vector_type(4))) int int4v;

__device__ __forceinline__ float bf2f(u16 u) {
    union { uint32_t i; float f; } c; c.i = ((uint32_t)u) << 16; return c.f;
}
__device__ __forceinline__ u16 f2bf(float f) {
    union { float f; uint32_t i; } c; c.f = f;
    uint32_t x = c.i;
    x += 0x7fffu + ((x >> 16) & 1u);
    return (u16)(x >> 16);
}
#define LOG2E 1.44269504f
__device__ __forceinline__ float silu_fast(float v) {
    return v * __builtin_amdgcn_rcpf(1.0f + __builtin_amdgcn_exp2f(v * -LOG2E));
}

#define GLDS16(gp, lp) __builtin_amdgcn_global_load_lds( \
        (const __attribute__((address_space(1))) void*)(gp), \
        (__attribute__((address_space(3))) void*)(lp), 16, 0, 0)

__device__ __forceinline__ int xcd_work(int flat, int nwg) {
    return ((flat & 7) * (nwg >> 3)) + (flat >> 3);
}

// ---------------- fused weight prep: 7 transposes + pb transpose ----------------
__global__ __launch_bounds__(256) void transpose_all_kernel(
    const float* __restrict__ wq, const float* __restrict__ wk,
    const float* __restrict__ wv, const float* __restrict__ wu,
    const float* __restrict__ w0, const float* __restrict__ w2,
    const float* __restrict__ w1,
    u16* __restrict__ wT4, u16* __restrict__ w0T,
    u16* __restrict__ w2T, u16* __restrict__ w1T,
    const float* __restrict__ pb, float* __restrict__ pbT)
{
    const unsigned MI = 1u << 20;
    const int z = blockIdx.z;
    const int tid = threadIdx.x;
    if (z == 8) {
        if (blockIdx.y != 0) return;
        const int r = (blockIdx.x << 7) + (tid >> 1);
        const int c0 = (tid & 1) << 3;
        float4 v0 = *(const float4*)&pb[(size_t)r * NH + c0];
        float4 v1 = *(const float4*)&pb[(size_t)r * NH + c0 + 4];
        pbT[(size_t)(c0 + 0) * S_ + r] = v0.x;
        pbT[(size_t)(c0 + 1) * S_ + r] = v0.y;
        pbT[(size_t)(c0 + 2) * S_ + r] = v0.z;
        pbT[(size_t)(c0 + 3) * S_ + r] = v0.w;
        pbT[(size_t)(c0 + 4) * S_ + r] = v1.x;
        pbT[(size_t)(c0 + 5) * S_ + r] = v1.y;
        pbT[(size_t)(c0 + 6) * S_ + r] = v1.z;
        pbT[(size_t)(c0 + 7) * S_ + r] = v1.w;
        return;
    }
    const float* W; u16* WT; int N; int noff = 0;
    switch (z) {
        case 0: W = wq; WT = wT4;          N = 1024; break;
        case 1: W = wk; WT = wT4 + 1 * MI; N = 1024; break;
        case 2: W = wv; WT = wT4 + 2 * MI; N = 1024; break;
        case 3: W = wu; WT = wT4 + 3 * MI; N = 1024; break;
        case 4: W = w0; WT = w0T;          N = 1024; break;
        case 5: W = w2; WT = w2T;          N = 1024; break;
        case 6: W = w1; WT = w1T;          N = 2048; noff = 0;    break;
        default:W = w1; WT = w1T;          N = 2048; noff = 1024; break;
    }
    __shared__ float T[64][65];
    const int n0 = (blockIdx.x << 6) + noff;
    const int k0 = blockIdx.y << 6;
    const int rr = tid >> 4;
    const int cc = (tid & 15) << 2;
#pragma unroll
    for (int l = 0; l < 4; ++l) {
        const int r = rr + (l << 4);
        float4 v = *(const float4*)&W[(size_t)(k0 + r) * N + n0 + cc];
        T[cc + 0][r] = v.x; T[cc + 1][r] = v.y;
        T[cc + 2][r] = v.z; T[cc + 3][r] = v.w;
    }
    __syncthreads();
    const int n  = tid >> 2;
    const int ks = (tid & 3) << 4;
#pragma unroll
    for (int m = 0; m < 4; ++m) {
        const int k = ks + (m << 2);
        float4 v = *(const float4*)&T[n][k];
        ushort4 o;
        o.x = f2bf(v.x); o.y = f2bf(v.y); o.z = f2bf(v.z); o.w = f2bf(v.w);
        *(ushort4*)&WT[(size_t)(n0 + n) * 1024 + k0 + k] = o;
    }
}

// ---------------- RMSNorm ----------------
__global__ __launch_bounds__(256) void rmsnorm_kernel(
    const float* __restrict__ inf, const u16* __restrict__ inb, int ldi,
    const float* __restrict__ g,
    const u16* __restrict__ mul, int ldm,
    u16* __restrict__ out, int ldo)
{
    const int row = blockIdx.x;
    const int tid = threadIdx.x;
    const int c = tid << 2;
    float x0, x1, x2, x3;
    if (inb) {
        ushort4 xi = *(const ushort4*)&inb[(size_t)row * ldi + c];
        x0 = bf2f(xi.x); x1 = bf2f(xi.y); x2 = bf2f(xi.z); x3 = bf2f(xi.w);
    } else {
        float4 xi = *(const float4*)&inf[(size_t)row * ldi + c];
        x0 = xi.x; x1 = xi.y; x2 = xi.z; x3 = xi.w;
    }
    float ss = x0*x0 + x1*x1 + x2*x2 + x3*x3;
#pragma unroll
    for (int off = 32; off > 0; off >>= 1) ss += __shfl_down(ss, off, 64);
    __shared__ float red[4];
    if ((tid & 63) == 0) red[tid >> 6] = ss;
    __syncthreads();
    float r = rsqrtf((red[0] + red[1] + red[2] + red[3]) * (1.0f / D) + EPSR);
    float4 gv = *(const float4*)&g[c];
    float v0 = x0 * r * gv.x, v1 = x1 * r * gv.y, v2 = x2 * r * gv.z, v3 = x3 * r * gv.w;
    if (mul) {
        ushort4 mi = *(const ushort4*)&mul[(size_t)row * ldm + c];
        v0 *= bf2f(mi.x); v1 *= bf2f(mi.y); v2 *= bf2f(mi.z); v3 *= bf2f(mi.w);
    }
    ushort4 o;
    o.x = f2bf(v0); o.y = f2bf(v1); o.z = f2bf(v2); o.w = f2bf(v3);
    *(ushort4*)&out[(size_t)row * ldo + c] = o;
}

// ---------------- 256x256 8-phase MFMA GEMM (QKVU), bf16 out ----------------
// 8 waves (2Mx4N), per-wave 128x64 output, BK=64, 2 K-tiles/iter, 8 phases.
// Swizzle: phys chunk = c ^ (row&7), pre-swizzled global source (r16/r17-proven).
__global__ __launch_bounds__(512, 2) void gemm256(
    const u16* __restrict__ A, const u16* __restrict__ WT,
    const float* __restrict__ bs0, const float* __restrict__ bs1,
    const float* __restrict__ bs2, const float* __restrict__ bs3,
    u16* __restrict__ outb, int ldo, int actmask,
    u16* __restrict__ VT, int vtsel)
{
    __shared__ u16 As[2][256 * 64];
    __shared__ u16 Bs[2][256 * 64];
    const int tid  = threadIdx.x;
    const int wave = tid >> 6;
    const int lane = tid & 63;
    const int lm   = lane & 15;
    const int quad = lane >> 4;
    const int l7x  = lm & 7;
    const int wm   = wave >> 2;          // M half
    const int wn   = wave & 3;           // N quarter
    const int work = xcd_work(blockIdx.x, 256);
    const int row0 = (work >> 4) << 8;
    const int col0 = (work & 15) << 8;

    // staging: wave covers rows [16w,16w+16) of a 128-row half; 2 glds (8 rows each)
    const int lr8  = lane >> 3;
    const int gch8 = ((lane & 7) ^ lr8) << 3;
    const u16* Ag = A  + (size_t)(row0 + 16 * wave + lr8) * 1024 + gch8;
    const u16* Bg = WT + (size_t)(col0 + 16 * wave + lr8) * 1024 + gch8;

#define STG(arr, buf, hf, gbase, kofs) do { \
        u16* dst = &arr[buf][((hf) * 128 + 16 * wave) * 64]; \
        GLDS16(gbase + (size_t)((hf) * 128) * 1024 + (kofs), dst); \
        GLDS16(gbase + (size_t)((hf) * 128 + 8) * 1024 + (kofs), dst + 8 * 64); \
    } while (0)
#define PH_BARRIER() do { asm volatile("" ::: "memory"); \
        __builtin_amdgcn_s_barrier(); asm volatile("" ::: "memory"); } while (0)
#define PH_COMPUTE(buf, q) do { \
        short8 af[2][2]; \
        _Pragma("unroll") \
        for (int ii = 0; ii < 2; ++ii) \
            _Pragma("unroll") \
            for (int kk = 0; kk < 2; ++kk) \
                af[ii][kk] = *(const short8*)&As[buf][(128 * wm + 16 * (2 * (q) + ii) + lm) * 64 + \
                                                     (((kk * 4 + quad) ^ l7x) << 3)]; \
        if ((q) == 0) { \
            _Pragma("unroll") \
            for (int n = 0; n < 4; ++n) \
                _Pragma("unroll") \
                for (int kk = 0; kk < 2; ++kk) \
                    bf[n][kk] = *(const short8*)&Bs[buf][(64 * wn + 16 * n + lm) * 64 + \
                                                         (((kk * 4 + quad) ^ l7x) << 3)]; \
        } \
        __builtin_amdgcn_s_setprio(1); \
        _Pragma("unroll") \
        for (int ii = 0; ii < 2; ++ii) \
            _Pragma("unroll") \
            for (int n = 0; n < 4; ++n) \
                _Pragma("unroll") \
                for (int kk = 0; kk < 2; ++kk) \
                    acc[2 * (q) + ii][n] = __builtin_amdgcn_mfma_f32_16x16x32_bf16( \
                        af[ii][kk], bf[n][kk], acc[2 * (q) + ii][n], 0, 0, 0); \
        __builtin_amdgcn_s_setprio(0); \
    } while (0)

    f32x4 acc[8][4] = {};
    short8 bf[4][2];

    // prologue: t0-B, t0-A (oldest 8 loads), then t1-B (4 loads)
    STG(Bs, 0, 0, Bg, 0); STG(Bs, 0, 1, Bg, 0);
    STG(As, 0, 0, Ag, 0); STG(As, 0, 1, Ag, 0);
    STG(Bs, 1, 0, Bg, 64); STG(Bs, 1, 1, Bg, 64);

#pragma unroll 1
    for (int i7 = 0; i7 < 8; ++i7) {
        const int t1k = (2 * i7 + 1) * 64;
        const int t2k = t1k + 64;
        const int t3k = t2k + 64;
        const bool more = (i7 < 7);
        // phase 1: wait t0 complete (leaves 4 newest = t1-B)
        asm volatile("s_waitcnt vmcnt(4)" ::: "memory");
        PH_BARRIER();
        STG(As, 1, 0, Ag, t1k);
        PH_COMPUTE(0, 0);
        // phase 2
        PH_BARRIER();
        STG(As, 1, 1, Ag, t1k);
        PH_COMPUTE(0, 1);
        // phase 3
        PH_BARRIER();
        if (more) STG(Bs, 0, 0, Bg, t2k);
        PH_COMPUTE(0, 2);
        // phase 4
        PH_BARRIER();
        if (more) STG(Bs, 0, 1, Bg, t2k);
        PH_COMPUTE(0, 3);
        // phase 5: wait t1 complete
        if (more) asm volatile("s_waitcnt vmcnt(4)" ::: "memory");
        else      asm volatile("s_waitcnt vmcnt(0)" ::: "memory");
        PH_BARRIER();
        if (more) STG(As, 0, 0, Ag, t2k);
        PH_COMPUTE(1, 0);
        // phase 6
        PH_BARRIER();
        if (more) STG(As, 0, 1, Ag, t2k);
        PH_COMPUTE(1, 1);
        // phase 7
        PH_BARRIER();
        if (more) STG(Bs, 1, 0, Bg, t3k);
        PH_COMPUTE(1, 2);
        // phase 8
        PH_BARRIER();
        if (more) STG(Bs, 1, 1, Bg, t3k);
        PH_COMPUTE(1, 3);
    }
#undef PH_COMPUTE
#undef PH_BARRIER
#undef STG

    const int sel = col0 >> 10;
    const float* bias = (sel == 0) ? bs0 : (sel == 1) ? bs1 : (sel == 2) ? bs2 : bs3;
    const int act = (actmask >> sel) & 1;
    if (VT && sel == vtsel) {
        const int b = row0 >> 11;
#pragma unroll
        for (int n = 0; n < 4; ++n) {
            const int c2 = (col0 + 64 * wn + 16 * n + lm) & 1023;
            const int h  = c2 >> 6;
            const int dh = c2 & 63;
            const float bj = bias[c2];
            u16* vrow = VT + ((size_t)(b * NH + h) * 64 + dh) * (size_t)S_;
#pragma unroll
            for (int i = 0; i < 8; ++i) {
                const int tb = (row0 & 2047) + 128 * wm + 16 * i + quad * 4;
                ushort4 o;
                o.x = f2bf(acc[i][n][0] + bj);
                o.y = f2bf(acc[i][n][1] + bj);
                o.z = f2bf(acc[i][n][2] + bj);
                o.w = f2bf(acc[i][n][3] + bj);
                *(ushort4*)&vrow[tb] = o;
            }
        }
    } else {
#pragma unroll
        for (int n = 0; n < 4; ++n) {
            const int colg = col0 + 64 * wn + 16 * n + lm;
            const float bj = bias[colg & 1023];
#pragma unroll
            for (int i = 0; i < 8; ++i) {
#pragma unroll
                for (int r = 0; r < 4; ++r) {
                    const int rowg = row0 + 128 * wm + 16 * i + quad * 4 + r;
                    float v = acc[i][n][r] + bj;
                    if (act) v = silu_fast(v);
                    outb[(size_t)rowg * ldo + colg] = f2bf(v);
                }
            }
        }
    }
}

// ---------------- 128x64 MFMA GEMM, BK=64, swizzled (w0, w2) -- r17 ----------------
__global__ __launch_bounds__(256) void gemm64(
    const u16* __restrict__ A, int lda, const u16* __restrict__ WT,
    const float* __restrict__ bias,
    const float* __restrict__ res,
    float* __restrict__ outf, int ldo)
{
    __shared__ u16 As[128 * 64];
    __shared__ u16 Bs[64 * 64];
    const int tid  = threadIdx.x;
    const int wave = tid >> 6;
    const int lane = tid & 63;
    const int lm   = lane & 15;
    const int quad = lane >> 4;
    const int l7   = lm & 7;
    const int gx   = gridDim.x;
    const int gxm  = gx - 1;
    const int gxs  = __popc(gxm);
    const int work = xcd_work(blockIdx.x + (blockIdx.y << gxs), gx * gridDim.y);
    const int col0 = (work & gxm) << 6;
    const int row0 = (work >> gxs) << 7;
    const int wr = (wave >> 1) << 6;
    const int wc = (wave & 1) << 5;

    const int lr8  = lane >> 3;
    const int gch8 = ((lane & 7) ^ lr8) << 3;
    const u16* Ag = A  + (size_t)(row0 + wave * 32 + lr8) * lda + gch8;
    const u16* Bg = WT + (size_t)(col0 + wave * 16 + lr8) * 1024 + gch8;

    f32x4 acc[4][2] = {};

    for (int k0 = 0; k0 < 1024; k0 += 64) {
        __syncthreads();
#pragma unroll
        for (int j = 0; j < 4; ++j)
            GLDS16(Ag + (size_t)(8 * j) * lda + k0, &As[(wave * 32 + 8 * j) * 64]);
#pragma unroll
        for (int j = 0; j < 2; ++j)
            GLDS16(Bg + (size_t)(8 * j) * 1024 + k0, &Bs[(wave * 16 + 8 * j) * 64]);
        __syncthreads();
#pragma unroll
        for (int kk = 0; kk < 2; ++kk) {
            short8 af[4], bf[2];
#pragma unroll
            for (int i = 0; i < 4; ++i)
                af[i] = *(const short8*)&As[(wr + i * 16 + lm) * 64 +
                                            (((kk * 4 + quad) ^ l7) << 3)];
#pragma unroll
            for (int j = 0; j < 2; ++j)
                bf[j] = *(const short8*)&Bs[(wc + j * 16 + lm) * 64 +
                                            (((kk * 4 + quad) ^ l7) << 3)];
#pragma unroll
            for (int i = 0; i < 4; ++i)
#pragma unroll
                for (int j = 0; j < 2; ++j)
                    acc[i][j] = __builtin_amdgcn_mfma_f32_16x16x32_bf16(af[i], bf[j], acc[i][j], 0, 0, 0);
        }
    }
#pragma unroll
    for (int j = 0; j < 2; ++j) {
        const int colg = col0 + wc + j * 16 + lm;
        const float bj = bias[colg];
#pragma unroll
        for (int i = 0; i < 4; ++i) {
#pragma unroll
            for (int r = 0; r < 4; ++r) {
                const int rowg = row0 + wr + i * 16 + quad * 4 + r;
                const size_t idx = (size_t)rowg * ldo + colg;
                float v = acc[i][j][r] + bj;
                if (res) v += res[idx];
                outf[idx] = v;
            }
        }
    }
}

// ---------------- w1 GEMM + fused SwiGLU, BK=64, swizzled -- r17 ----------------
__global__ __launch_bounds__(256) void gemm_w1_swiglu(
    const u16* __restrict__ A, const u16* __restrict__ WT,
    const float* __restrict__ b1, u16* __restrict__ outb)
{
    __shared__ u16 As[128 * 64];
    __shared__ u16 Bs[128 * 64];
    const int tid  = threadIdx.x;
    const int wave = tid >> 6;
    const int lane = tid & 63;
    const int lm   = lane & 15;
    const int quad = lane >> 4;
    const int l7   = lm & 7;
    const int gx   = gridDim.x;
    const int gxm  = gx - 1;
    const int gxs  = __popc(gxm);
    const int work = xcd_work(blockIdx.x + (blockIdx.y << gxs), gx * gridDim.y);
    const int col0 = (work & gxm) << 6;       // swiglu output cols
    const int row0 = (work >> gxs) << 7;
    const int wr  = (wave >> 1) << 6;
    const int wc2 = (wave & 1) << 5;

    const int lr8  = lane >> 3;
    const int gch8 = ((lane & 7) ^ lr8) << 3;
    const int sb   = wave * 32;
    const int brow = col0 + (sb & 63) + ((sb >> 6) << 10) + lr8;
    const u16* Ag = A  + (size_t)(row0 + wave * 32 + lr8) * 1024 + gch8;
    const u16* Bg = WT + (size_t)brow * 1024 + gch8;

    f32x4 acc[4][4] = {};

    for (int k0 = 0; k0 < 1024; k0 += 64) {
        __syncthreads();
#pragma unroll
        for (int j = 0; j < 4; ++j) {
            GLDS16(Ag + (size_t)(8 * j) * 1024 + k0, &As[(wave * 32 + 8 * j) * 64]);
            GLDS16(Bg + (size_t)(8 * j) * 1024 + k0, &Bs[(wave * 32 + 8 * j) * 64]);
        }
        __syncthreads();
#pragma unroll
        for (int kk = 0; kk < 2; ++kk) {
            short8 af[4], bf[4];
#pragma unroll
            for (int i = 0; i < 4; ++i)
                af[i] = *(const short8*)&As[(wr + i * 16 + lm) * 64 +
                                            (((kk * 4 + quad) ^ l7) << 3)];
#pragma unroll
            for (int j = 0; j < 2; ++j) {
                bf[j]     = *(const short8*)&Bs[(wc2 + j * 16 + lm) * 64 +
                                                (((kk * 4 + quad) ^ l7) << 3)];
                bf[j + 2] = *(const short8*)&Bs[(64 + wc2 + j * 16 + lm) * 64 +
                                                (((kk * 4 + quad) ^ l7) << 3)];
            }
#pragma unroll
            for (int i = 0; i < 4; ++i)
#pragma unroll
                for (int j = 0; j < 4; ++j)
                    acc[i][j] = __builtin_amdgcn_mfma_f32_16x16x32_bf16(af[i], bf[j], acc[i][j], 0, 0, 0);
        }
    }
#pragma unroll
    for (int j = 0; j < 2; ++j) {
        const int colg = col0 + wc2 + j * 16 + lm;
        const float ba = b1[colg];
        const float bb = b1[1024 + colg];
#pragma unroll
        for (int i = 0; i < 4; ++i) {
#pragma unroll
            for (int r = 0; r < 4; ++r) {
                const int rowg = row0 + wr + i * 16 + quad * 4 + r;
                const float x1v = acc[i][j][r] + ba;
                const float x2v = acc[i][j + 2][r] + bb;
                outb[(size_t)rowg * LQ + colg] = f2bf(silu_fast(x1v) * x2v);
            }
        }
    }
}

// ---------------- MFMA SiLU attention (unchanged from r16/r17) ----------------
__global__ __launch_bounds__(512, 2) void attn_mfma(
    const u16* __restrict__ qkvu, const u16* __restrict__ VT,
    const float* __restrict__ pbT, u16* __restrict__ out)
{
    __shared__ u16 Ks[2][2][64 * 64];   // [group][buf]
    __shared__ u16 Vs[2][2][64 * 64];
    __shared__ float pbl[S_];
    const int tid  = threadIdx.x;
    const int wave = tid >> 6;
    const int grp  = wave >> 2;         // t-half
    const int wq4  = wave & 3;          // q sub-tile
    const int lane = tid & 63;
    const int l31  = lane & 31;
    const int hi   = lane >> 5;
    const int l7   = lane & 7;
    const int xorv = l7 ^ ((l31 >> 3) & 3);   // read-side swizzle key
    const int flat = blockIdx.x + (blockIdx.y << 4) + (blockIdx.z << 8);
    const int work = ((flat & 7) << 6) + (flat >> 3);
    const int s0 = (work & 15) << 7;
    const int h  = (work >> 4) & 15;
    const int b  = work >> 8;
    const size_t base = (size_t)b * S_ * LQ + (size_t)h * DH;
    const u16* q  = qkvu + base;
    const u16* kg = qkvu + base + 1024;
    const u16* vt = VT + (size_t)(b * NH + h) * 64 * S_;
    const float* pbh = pbT + (size_t)h * S_;

    for (int i = tid * 4; i < S_; i += 2048)
        *(float4*)&pbl[i] = *(const float4*)&pbh[i];

    const int qrow = s0 + wq4 * 32 + l31;
    short8 qf[4];
#pragma unroll
    for (int i = 0; i < 4; ++i)
        qf[i] = *(const short8*)&q[(size_t)qrow * LQ + i * 16 + hi * 8];

    const int lr  = lane >> 3;
    const int gA  = (2 * wq4) & 3;
    const int gB  = (2 * wq4 + 1) & 3;
    const u16* kgA = kg + (size_t)(16 * wq4 + lr) * LQ     + ((l7 ^ lr ^ gA) << 3);
    const u16* kgB = kg + (size_t)(16 * wq4 + 8 + lr) * LQ + ((l7 ^ lr ^ gB) << 3);
    const u16* vgA = vt + (size_t)(16 * wq4 + lr) * S_     + ((l7 ^ lr ^ gA) << 3);
    const u16* vgB = vt + (size_t)(16 * wq4 + 8 + lr) * S_ + ((l7 ^ lr ^ gB) << 3);

#define ISSUE(it, bu) do { \
        const size_t tn = ((size_t)(grp) * 16 + (size_t)(it)) << 6; \
        GLDS16(kgA + tn * LQ, &Ks[grp][bu][(16 * wq4) * 64]); \
        GLDS16(kgB + tn * LQ, &Ks[grp][bu][(16 * wq4 + 8) * 64]); \
        GLDS16(vgA + tn,      &Vs[grp][bu][(16 * wq4) * 64]); \
        GLDS16(vgB + tn,      &Vs[grp][bu][(16 * wq4 + 8) * 64]); \
    } while (0)

    f32x16 accO[2] = {};
    ISSUE(0, 0);
    __syncthreads();

#pragma unroll 1
    for (int it = 0; it < 16; ++it) {
        const int ib = it & 1;
        const int nb = ib ^ 1;
        if (it + 1 < 16) ISSUE(it + 1, nb);
        const int t0 = grp * 1024 + (it << 6);
        f32x16 st0 = {}, st1 = {};
        __builtin_amdgcn_s_setprio(1);
#pragma unroll
        for (int i = 0; i < 4; ++i) {
            const int co = ((2 * i + hi) ^ xorv) << 3;
            short8 kf0 = *(const short8*)&Ks[grp][ib][(l31) * 64 + co];
            short8 kf1 = *(const short8*)&Ks[grp][ib][(32 + l31) * 64 + co];
            st0 = __builtin_amdgcn_mfma_f32_32x32x16_bf16(kf0, qf[i], st0, 0, 0, 0);
            st1 = __builtin_amdgcn_mfma_f32_32x32x16_bf16(kf1, qf[i], st1, 0, 0, 0);
        }
        __builtin_amdgcn_s_setprio(0);
        int pk0[8], pk1[8];
#pragma unroll
        for (int g = 0; g < 4; ++g) {
            float4 pbv0 = *(const float4*)&pbl[t0 + 8 * g + 4 * hi];
            float4 pbv1 = *(const float4*)&pbl[t0 + 32 + 8 * g + 4 * hi];
            float a0 = silu_fast(fmaf(st0[4 * g + 0], 0.125f, pbv0.x));
            float a1 = silu_fast(fmaf(st0[4 * g + 1], 0.125f, pbv0.y));
            float a2 = silu_fast(fmaf(st0[4 * g + 2], 0.125f, pbv0.z));
            float a3 = silu_fast(fmaf(st0[4 * g + 3], 0.125f, pbv0.w));
            float b0 = silu_fast(fmaf(st1[4 * g + 0], 0.125f, pbv1.x));
            float b1 = silu_fast(fmaf(st1[4 * g + 1], 0.125f, pbv1.y));
            float b2 = silu_fast(fmaf(st1[4 * g + 2], 0.125f, pbv1.z));
            float b3 = silu_fast(fmaf(st1[4 * g + 3], 0.125f, pbv1.w));
            asm("v_cvt_pk_bf16_f32 %0, %1, %2" : "=v"(pk0[2 * g])     : "v"(a0), "v"(a1));
            asm("v_cvt_pk_bf16_f32 %0, %1, %2" : "=v"(pk0[2 * g + 1]) : "v"(a2), "v"(a3));
            asm("v_cvt_pk_bf16_f32 %0, %1, %2" : "=v"(pk1[2 * g])     : "v"(b0), "v"(b1));
            asm("v_cvt_pk_bf16_f32 %0, %1, %2" : "=v"(pk1[2 * g + 1]) : "v"(b2), "v"(b3));
        }
#pragma unroll
        for (int m = 0; m < 2; ++m) {
            int w0 = pk0[4 * m + 0], w2 = pk0[4 * m + 2];
            int w1 = pk0[4 * m + 1], w3 = pk0[4 * m + 3];
            asm("v_permlane32_swap_b32 %0, %1" : "+v"(w0), "+v"(w2));
            asm("v_permlane32_swap_b32 %0, %1" : "+v"(w1), "+v"(w3));
            int u0 = pk1[4 * m + 0], u2 = pk1[4 * m + 2];
            int u1 = pk1[4 * m + 1], u3 = pk1[4 * m + 3];
            asm("v_permlane32_swap_b32 %0, %1" : "+v"(u0), "+v"(u2));
            asm("v_permlane32_swap_b32 %0, %1" : "+v"(u1), "+v"(u3));
            union { int4v i; short8 s; } pa, pb2;
            pa.i.x  = w0; pa.i.y  = w1; pa.i.z  = w2; pa.i.w  = w3;
            pb2.i.x = u0; pb2.i.y = u1; pb2.i.z = u2; pb2.i.w = u3;
            __builtin_amdgcn_s_setprio(1);
#pragma unroll
            for (int n = 0; n < 2; ++n) {
                short8 vf0 = *(const short8*)&Vs[grp][ib][(32 * n + l31) * 64 +
                    (((2 * m + hi) ^ xorv) << 3)];
                short8 vf1 = *(const short8*)&Vs[grp][ib][(32 * n + l31) * 64 +
                    (((4 + 2 * m + hi) ^ xorv) << 3)];
                accO[n] = __builtin_amdgcn_mfma_f32_32x32x16_bf16(pa.s,  vf0, accO[n], 0, 0, 0);
                accO[n] = __builtin_amdgcn_mfma_f32_32x32x16_bf16(pb2.s, vf1, accO[n], 0, 0, 0);
            }
            __builtin_amdgcn_s_setprio(0);
        }
        __syncthreads();
    }
#undef ISSUE
    float* scr = (float*)&Ks[0][0][0];
    const int sl = wq4 * 64 + lane;
    if (grp == 1) {
#pragma unroll
        for (int n = 0; n < 2; ++n)
#pragma unroll
            for (int r = 0; r < 16; ++r)
                scr[(n * 16 + r) * 256 + sl] = accO[n][r];
    }
    __syncthreads();
    if (grp == 0) {
#pragma unroll
        for (int n = 0; n < 2; ++n)
#pragma unroll
            for (int r = 0; r < 16; ++r)
                accO[n][r] += scr[(n * 16 + r) * 256 + sl];
        const int qb = s0 + wq4 * 32 + 4 * hi;
#pragma unroll
        for (int n = 0; n < 2; ++n)
#pragma unroll
            for (int r = 0; r < 16; ++r) {
                const int qq = qb + (r & 3) + 8 * (r >> 2);
                out[base + (size_t)qq * LQ + 32 * n + l31] = f2bf(accO[n][r]);
            }
    }
}

extern "C" void kernel_launch(void* const* d_in, const int* in_sizes, int n_in,
                              void* d_out, int out_size, void* d_ws, size_t ws_size,
                              hipStream_t stream)
{
    const float* x      = (const float*)d_in[0];
    const float* pb     = (const float*)d_in[2];
    const float* wq     = (const float*)d_in[3];
    const float* bq     = (const float*)d_in[4];
    const float* wk     = (const float*)d_in[5];
    const float* bk     = (const float*)d_in[6];
    const float* wv     = (const float*)d_in[7];
    const float* bv     = (const float*)d_in[8];
    const float* wu     = (const float*)d_in[9];
    const float* bu     = (const float*)d_in[10];
    const float* g_ams  = (const float*)d_in[11];
    const float* w0     = (const float*)d_in[12];
    const float* b0     = (const float*)d_in[13];
    const float* w1     = (const float*)d_in[14];
    const float* b1     = (const float*)d_in[15];
    const float* w2     = (const float*)d_in[16];
    const float* b2     = (const float*)d_in[17];
    const float* g_mffn = (const float*)d_in[18];
    float* OUT = (float*)d_out;
    u16*   VT  = (u16*)d_out;              // VT[b][h][64][2048] (8 MB) — dead after attn
    float* pbT = (float*)((u16*)d_out + 4 * (1u << 20));  // 128KB at +8MB — dead after attn

    const size_t MI = 1024 * 1024;
    u16* WS   = (u16*)d_ws;                // 56 MB total
    u16* wT4  = WS;
    u16* w0T  = WS + 4 * MI;
    u16* w2T  = WS + 5 * MI;
    u16* w1T  = WS + 6 * MI;
    u16* A0   = WS + 8 * MI;
    u16* QKVU = WS + 12 * MI;

    dim3 blk(256);

    transpose_all_kernel<<<dim3(16, 16, 9), blk, 0, stream>>>(
        wq, wk, wv, wu, w0, w2, w1, wT4, w0T, w2T, w1T, pb, pbT);

    rmsnorm_kernel<<<ROWS, blk, 0, stream>>>(x, nullptr, D, g_ams, nullptr, 0, A0, D);
    gemm256<<<dim3(256), dim3(512), 0, stream>>>(A0, wT4, bq, bk, bv, bu,
                                                 QKVU, LQ, 0b1000, VT, 2);
    attn_mfma<<<dim3(16, 16, 2), dim3(512), 0, stream>>>(QKVU, VT, pbT, QKVU);
    rmsnorm_kernel<<<ROWS, blk, 0, stream>>>(nullptr, QKVU, LQ, g_ams, QKVU + 3072, LQ, A0, D);
    gemm64<<<dim3(16, 32), blk, 0, stream>>>(A0, D, w0T, b0, x, OUT, D);
    rmsnorm_kernel<<<ROWS, blk, 0, stream>>>(OUT, nullptr, D, g_mffn, nullptr, 0, A0, D);
    gemm_w1_swiglu<<<dim3(16, 32), blk, 0, stream>>>(A0, w1T, b1, QKVU + 2048);
    gemm64<<<dim3(16, 32), blk, 0, stream>>>(QKVU + 2048, LQ, w2T, b2, OUT, OUT, D);
    (void)ws_size; (void)in_sizes; (void)n_in; (void)out_size;
}

// Round 11
// 295.507 us; speedup vs baseline: 1.0232x; 1.0232x over previous
//
#include <hip/hip_runtime.h>
#include <stdint.h>
#include <math.h>

// FuXi block on MI355X, round 20: small-GEMM occupancy split.
// r19 post-mortem: 8-phase 256^2 QKVU null (+4.6) -- second scheduling null in a row;
// at K=1024 (16 K-steps) the schedule isn't binding. Reverted QKVU to r17 gemm128.
// r20 target: w0/w2/w1 GEMMs are GRID-limited to 2 blocks/CU (512 blocks) while
// having tiny LDS -- the same starvation attn had pre-r15. Split to 64-row tiles:
// grid 1024 = 4 blocks/CU (4 waves/SIMD TLP hides the 2-phase stage drain, m114).
// gemm64: 64x64 tile, wave=32x32, 16KB LDS. gemm_w1: 64rows x 64cols (128 B-rows),
// wave = 32x32 x1 + 32x32 x2, 24KB LDS. Same BK=64 + XOR swizzle + XCD swizzle.
// attn + gemm128 unchanged (controls).

#define D    1024
#define NH   16
#define DH   64
#define B_   2
#define S_   2048
#define ROWS 4096
#define LQ   4096          // QKVU row stride
#define EPSR 1e-8f

typedef unsigned short u16;
typedef __attribute__((ext_vector_type(8))) short short8;
typedef __attribute__((ext_vector_type(4))) float f32x4;
typedef __attribute__((ext_vector_type(16))) float f32x16;
typedef __attribute__((ext_vector_type(4))) int int4v;

__device__ __forceinline__ float bf2f(u16 u) {
    union { uint32_t i; float f; } c; c.i = ((uint32_t)u) << 16; return c.f;
}
__device__ __forceinline__ u16 f2bf(float f) {
    union { float f; uint32_t i; } c; c.f = f;
    uint32_t x = c.i;
    x += 0x7fffu + ((x >> 16) & 1u);
    return (u16)(x >> 16);
}
#define LOG2E 1.44269504f
__device__ __forceinline__ float silu_fast(float v) {
    return v * __builtin_amdgcn_rcpf(1.0f + __builtin_amdgcn_exp2f(v * -LOG2E));
}

#define GLDS16(gp, lp) __builtin_amdgcn_global_load_lds( \
        (const __attribute__((address_space(1))) void*)(gp), \
        (__attribute__((address_space(3))) void*)(lp), 16, 0, 0)

__device__ __forceinline__ int xcd_work(int flat, int nwg) {
    return ((flat & 7) * (nwg >> 3)) + (flat >> 3);
}

// ---------------- fused weight prep: 7 transposes + pb transpose ----------------
__global__ __launch_bounds__(256) void transpose_all_kernel(
    const float* __restrict__ wq, const float* __restrict__ wk,
    const float* __restrict__ wv, const float* __restrict__ wu,
    const float* __restrict__ w0, const float* __restrict__ w2,
    const float* __restrict__ w1,
    u16* __restrict__ wT4, u16* __restrict__ w0T,
    u16* __restrict__ w2T, u16* __restrict__ w1T,
    const float* __restrict__ pb, float* __restrict__ pbT)
{
    const unsigned MI = 1u << 20;
    const int z = blockIdx.z;
    const int tid = threadIdx.x;
    if (z == 8) {
        if (blockIdx.y != 0) return;
        const int r = (blockIdx.x << 7) + (tid >> 1);
        const int c0 = (tid & 1) << 3;
        float4 v0 = *(const float4*)&pb[(size_t)r * NH + c0];
        float4 v1 = *(const float4*)&pb[(size_t)r * NH + c0 + 4];
        pbT[(size_t)(c0 + 0) * S_ + r] = v0.x;
        pbT[(size_t)(c0 + 1) * S_ + r] = v0.y;
        pbT[(size_t)(c0 + 2) * S_ + r] = v0.z;
        pbT[(size_t)(c0 + 3) * S_ + r] = v0.w;
        pbT[(size_t)(c0 + 4) * S_ + r] = v1.x;
        pbT[(size_t)(c0 + 5) * S_ + r] = v1.y;
        pbT[(size_t)(c0 + 6) * S_ + r] = v1.z;
        pbT[(size_t)(c0 + 7) * S_ + r] = v1.w;
        return;
    }
    const float* W; u16* WT; int N; int noff = 0;
    switch (z) {
        case 0: W = wq; WT = wT4;          N = 1024; break;
        case 1: W = wk; WT = wT4 + 1 * MI; N = 1024; break;
        case 2: W = wv; WT = wT4 + 2 * MI; N = 1024; break;
        case 3: W = wu; WT = wT4 + 3 * MI; N = 1024; break;
        case 4: W = w0; WT = w0T;          N = 1024; break;
        case 5: W = w2; WT = w2T;          N = 1024; break;
        case 6: W = w1; WT = w1T;          N = 2048; noff = 0;    break;
        default:W = w1; WT = w1T;          N = 2048; noff = 1024; break;
    }
    __shared__ float T[64][65];
    const int n0 = (blockIdx.x << 6) + noff;
    const int k0 = blockIdx.y << 6;
    const int rr = tid >> 4;
    const int cc = (tid & 15) << 2;
#pragma unroll
    for (int l = 0; l < 4; ++l) {
        const int r = rr + (l << 4);
        float4 v = *(const float4*)&W[(size_t)(k0 + r) * N + n0 + cc];
        T[cc + 0][r] = v.x; T[cc + 1][r] = v.y;
        T[cc + 2][r] = v.z; T[cc + 3][r] = v.w;
    }
    __syncthreads();
    const int n  = tid >> 2;
    const int ks = (tid & 3) << 4;
#pragma unroll
    for (int m = 0; m < 4; ++m) {
        const int k = ks + (m << 2);
        float4 v = *(const float4*)&T[n][k];
        ushort4 o;
        o.x = f2bf(v.x); o.y = f2bf(v.y); o.z = f2bf(v.z); o.w = f2bf(v.w);
        *(ushort4*)&WT[(size_t)(n0 + n) * 1024 + k0 + k] = o;
    }
}

// ---------------- RMSNorm ----------------
__global__ __launch_bounds__(256) void rmsnorm_kernel(
    const float* __restrict__ inf, const u16* __restrict__ inb, int ldi,
    const float* __restrict__ g,
    const u16* __restrict__ mul, int ldm,
    u16* __restrict__ out, int ldo)
{
    const int row = blockIdx.x;
    const int tid = threadIdx.x;
    const int c = tid << 2;
    float x0, x1, x2, x3;
    if (inb) {
        ushort4 xi = *(const ushort4*)&inb[(size_t)row * ldi + c];
        x0 = bf2f(xi.x); x1 = bf2f(xi.y); x2 = bf2f(xi.z); x3 = bf2f(xi.w);
    } else {
        float4 xi = *(const float4*)&inf[(size_t)row * ldi + c];
        x0 = xi.x; x1 = xi.y; x2 = xi.z; x3 = xi.w;
    }
    float ss = x0*x0 + x1*x1 + x2*x2 + x3*x3;
#pragma unroll
    for (int off = 32; off > 0; off >>= 1) ss += __shfl_down(ss, off, 64);
    __shared__ float red[4];
    if ((tid & 63) == 0) red[tid >> 6] = ss;
    __syncthreads();
    float r = rsqrtf((red[0] + red[1] + red[2] + red[3]) * (1.0f / D) + EPSR);
    float4 gv = *(const float4*)&g[c];
    float v0 = x0 * r * gv.x, v1 = x1 * r * gv.y, v2 = x2 * r * gv.z, v3 = x3 * r * gv.w;
    if (mul) {
        ushort4 mi = *(const ushort4*)&mul[(size_t)row * ldm + c];
        v0 *= bf2f(mi.x); v1 *= bf2f(mi.y); v2 *= bf2f(mi.z); v3 *= bf2f(mi.w);
    }
    ushort4 o;
    o.x = f2bf(v0); o.y = f2bf(v1); o.z = f2bf(v2); o.w = f2bf(v3);
    *(ushort4*)&out[(size_t)row * ldo + c] = o;
}

// ---------------- 128x128 MFMA GEMM, BK=64, swizzled staging (r17) --------------
__global__ __launch_bounds__(256) void gemm128(
    const u16* __restrict__ A, const u16* __restrict__ WT,
    const float* __restrict__ bs0, const float* __restrict__ bs1,
    const float* __restrict__ bs2, const float* __restrict__ bs3,
    u16* __restrict__ outb, int ldo, int actmask,
    u16* __restrict__ VT, int vtsel)
{
    __shared__ u16 As[128 * 64];
    __shared__ u16 Bs[128 * 64];
    const int tid  = threadIdx.x;
    const int wave = tid >> 6;
    const int lane = tid & 63;
    const int lm   = lane & 15;
    const int quad = lane >> 4;
    const int l7   = lm & 7;
    const int gx   = gridDim.x;
    const int gxm  = gx - 1;
    const int gxs  = __popc(gxm);
    const int work = xcd_work(blockIdx.x + (blockIdx.y << gxs), gx * gridDim.y);
    const int col0 = (work & gxm) << 7;
    const int row0 = (work >> gxs) << 7;
    const int wr = (wave >> 1) << 6;
    const int wc = (wave & 1) << 6;

    const int lr8  = lane >> 3;
    const int gch8 = ((lane & 7) ^ lr8) << 3;
    const u16* Ag = A  + (size_t)(row0 + wave * 32 + lr8) * 1024 + gch8;
    const u16* Bg = WT + (size_t)(col0 + wave * 32 + lr8) * 1024 + gch8;

    f32x4 acc[4][4] = {};

    for (int k0 = 0; k0 < 1024; k0 += 64) {
        __syncthreads();
#pragma unroll
        for (int j = 0; j < 4; ++j) {
            GLDS16(Ag + (size_t)(8 * j) * 1024 + k0, &As[(wave * 32 + 8 * j) * 64]);
            GLDS16(Bg + (size_t)(8 * j) * 1024 + k0, &Bs[(wave * 32 + 8 * j) * 64]);
        }
        __syncthreads();
#pragma unroll
        for (int kk = 0; kk < 2; ++kk) {
            short8 af[4], bf[4];
#pragma unroll
            for (int i = 0; i < 4; ++i)
                af[i] = *(const short8*)&As[(wr + i * 16 + lm) * 64 +
                                            (((kk * 4 + quad) ^ l7) << 3)];
#pragma unroll
            for (int j = 0; j < 4; ++j)
                bf[j] = *(const short8*)&Bs[(wc + j * 16 + lm) * 64 +
                                            (((kk * 4 + quad) ^ l7) << 3)];
#pragma unroll
            for (int i = 0; i < 4; ++i)
#pragma unroll
                for (int j = 0; j < 4; ++j)
                    acc[i][j] = __builtin_amdgcn_mfma_f32_16x16x32_bf16(af[i], bf[j], acc[i][j], 0, 0, 0);
        }
    }
    const int sel = col0 >> 10;
    const float* bias = (sel == 0) ? bs0 : (sel == 1) ? bs1 : (sel == 2) ? bs2 : bs3;
    const int act = (actmask >> sel) & 1;
    if (VT && sel == vtsel) {
        // transposed write: VT[b][h][dh][t], t-consecutive regs -> ushort4 stores
        const int b = row0 >> 11;
#pragma unroll
        for (int j = 0; j < 4; ++j) {
            const int c2 = (col0 + wc + j * 16 + lm) & 1023;
            const int h  = c2 >> 6;
            const int dh = c2 & 63;
            const float bj = bias[c2];
            u16* vrow = VT + ((size_t)(b * NH + h) * 64 + dh) * (size_t)S_;
#pragma unroll
            for (int i = 0; i < 4; ++i) {
                const int tb = (row0 & 2047) + wr + i * 16 + quad * 4;
                ushort4 o;
                o.x = f2bf(acc[i][j][0] + bj);
                o.y = f2bf(acc[i][j][1] + bj);
                o.z = f2bf(acc[i][j][2] + bj);
                o.w = f2bf(acc[i][j][3] + bj);
                *(ushort4*)&vrow[tb] = o;
            }
        }
    } else {
#pragma unroll
        for (int j = 0; j < 4; ++j) {
            const int colg = col0 + wc + j * 16 + lm;
            const float bj = bias[colg & 1023];
#pragma unroll
            for (int i = 0; i < 4; ++i) {
#pragma unroll
                for (int r = 0; r < 4; ++r) {
                    const int rowg = row0 + wr + i * 16 + quad * 4 + r;
                    float v = acc[i][j][r] + bj;
                    if (act) v = silu_fast(v);
                    outb[(size_t)rowg * ldo + colg] = f2bf(v);
                }
            }
        }
    }
}

// ---------------- 64x64 MFMA GEMM, BK=64, swizzled (w0, w2), 4 blk/CU ------------
__global__ __launch_bounds__(256) void gemm64(
    const u16* __restrict__ A, int lda, const u16* __restrict__ WT,
    const float* __restrict__ bias,
    const float* __restrict__ res,
    float* __restrict__ outf, int ldo)
{
    __shared__ u16 As[64 * 64];
    __shared__ u16 Bs[64 * 64];
    const int tid  = threadIdx.x;
    const int wave = tid >> 6;
    const int lane = tid & 63;
    const int lm   = lane & 15;
    const int quad = lane >> 4;
    const int l7   = lm & 7;
    // grid 16 (cols) x 64 (rows) = 1024 blocks = 4/CU
    const int work = xcd_work(blockIdx.x + (blockIdx.y << 4), 1024);
    const int col0 = (work & 15) << 6;
    const int row0 = (work >> 4) << 6;
    const int wr = (wave >> 1) << 5;
    const int wc = (wave & 1) << 5;

    const int lr8  = lane >> 3;
    const int gch8 = ((lane & 7) ^ lr8) << 3;
    const u16* Ag = A  + (size_t)(row0 + wave * 16 + lr8) * lda + gch8;
    const u16* Bg = WT + (size_t)(col0 + wave * 16 + lr8) * 1024 + gch8;

    f32x4 acc[2][2] = {};

    for (int k0 = 0; k0 < 1024; k0 += 64) {
        __syncthreads();
        GLDS16(Ag + k0,                        &As[(wave * 16) * 64]);
        GLDS16(Ag + (size_t)8 * lda + k0,      &As[(wave * 16 + 8) * 64]);
        GLDS16(Bg + k0,                        &Bs[(wave * 16) * 64]);
        GLDS16(Bg + (size_t)8 * 1024 + k0,     &Bs[(wave * 16 + 8) * 64]);
        __syncthreads();
#pragma unroll
        for (int kk = 0; kk < 2; ++kk) {
            short8 af[2], bf[2];
#pragma unroll
            for (int i = 0; i < 2; ++i)
                af[i] = *(const short8*)&As[(wr + i * 16 + lm) * 64 +
                                            (((kk * 4 + quad) ^ l7) << 3)];
#pragma unroll
            for (int j = 0; j < 2; ++j)
                bf[j] = *(const short8*)&Bs[(wc + j * 16 + lm) * 64 +
                                            (((kk * 4 + quad) ^ l7) << 3)];
#pragma unroll
            for (int i = 0; i < 2; ++i)
#pragma unroll
                for (int j = 0; j < 2; ++j)
                    acc[i][j] = __builtin_amdgcn_mfma_f32_16x16x32_bf16(af[i], bf[j], acc[i][j], 0, 0, 0);
        }
    }
#pragma unroll
    for (int j = 0; j < 2; ++j) {
        const int colg = col0 + wc + j * 16 + lm;
        const float bj = bias[colg];
#pragma unroll
        for (int i = 0; i < 2; ++i) {
#pragma unroll
            for (int r = 0; r < 4; ++r) {
                const int rowg = row0 + wr + i * 16 + quad * 4 + r;
                const size_t idx = (size_t)rowg * ldo + colg;
                float v = acc[i][j][r] + bj;
                if (res) v += res[idx];
                outf[idx] = v;
            }
        }
    }
}

// ---------------- w1 GEMM + fused SwiGLU, 64x64 tiles, 4 blk/CU ----------------
__global__ __launch_bounds__(256) void gemm_w1_swiglu(
    const u16* __restrict__ A, const u16* __restrict__ WT,
    const float* __restrict__ b1, u16* __restrict__ outb)
{
    __shared__ u16 As[64 * 64];
    __shared__ u16 Bs[128 * 64];
    const int tid  = threadIdx.x;
    const int wave = tid >> 6;
    const int lane = tid & 63;
    const int lm   = lane & 15;
    const int quad = lane >> 4;
    const int l7   = lm & 7;
    const int work = xcd_work(blockIdx.x + (blockIdx.y << 4), 1024);
    const int col0 = (work & 15) << 6;        // swiglu output cols
    const int row0 = (work >> 4) << 6;
    const int wr  = (wave >> 1) << 5;
    const int wc2 = (wave & 1) << 5;

    const int lr8  = lane >> 3;
    const int gch8 = ((lane & 7) ^ lr8) << 3;
    // Bs rows 0..63 = x1 weights (w1T rows col0+..), 64..127 = x2 (w1T rows 1024+col0+..)
    const int sb   = wave * 32;               // Bs base row for this wave
    const int brow = col0 + (sb & 63) + ((sb >> 6) << 10) + lr8;
    const u16* Ag = A  + (size_t)(row0 + wave * 16 + lr8) * 1024 + gch8;
    const u16* Bg = WT + (size_t)brow * 1024 + gch8;

    f32x4 acc[2][4] = {};

    for (int k0 = 0; k0 < 1024; k0 += 64) {
        __syncthreads();
        GLDS16(Ag + k0,                   &As[(wave * 16) * 64]);
        GLDS16(Ag + (size_t)8 * 1024 + k0,&As[(wave * 16 + 8) * 64]);
#pragma unroll
        for (int j = 0; j < 4; ++j)
            GLDS16(Bg + (size_t)(8 * j) * 1024 + k0, &Bs[(wave * 32 + 8 * j) * 64]);
        __syncthreads();
#pragma unroll
        for (int kk = 0; kk < 2; ++kk) {
            short8 af[2], bf[4];
#pragma unroll
            for (int i = 0; i < 2; ++i)
                af[i] = *(const short8*)&As[(wr + i * 16 + lm) * 64 +
                                            (((kk * 4 + quad) ^ l7) << 3)];
#pragma unroll
            for (int j = 0; j < 2; ++j) {
                bf[j]     = *(const short8*)&Bs[(wc2 + j * 16 + lm) * 64 +
                                                (((kk * 4 + quad) ^ l7) << 3)];
                bf[j + 2] = *(const short8*)&Bs[(64 + wc2 + j * 16 + lm) * 64 +
                                                (((kk * 4 + quad) ^ l7) << 3)];
            }
#pragma unroll
            for (int i = 0; i < 2; ++i)
#pragma unroll
                for (int j = 0; j < 4; ++j)
                    acc[i][j] = __builtin_amdgcn_mfma_f32_16x16x32_bf16(af[i], bf[j], acc[i][j], 0, 0, 0);
        }
    }
#pragma unroll
    for (int j = 0; j < 2; ++j) {
        const int colg = col0 + wc2 + j * 16 + lm;
        const float ba = b1[colg];
        const float bb = b1[1024 + colg];
#pragma unroll
        for (int i = 0; i < 2; ++i) {
#pragma unroll
            for (int r = 0; r < 4; ++r) {
                const int rowg = row0 + wr + i * 16 + quad * 4 + r;
                const float x1v = acc[i][j][r] + ba;
                const float x2v = acc[i][j + 2][r] + bb;
                outb[(size_t)rowg * LQ + colg] = f2bf(silu_fast(x1v) * x2v);
            }
        }
    }
}

// ---------------- MFMA SiLU attention (unchanged from r16/r17) ----------------
__global__ __launch_bounds__(512, 2) void attn_mfma(
    const u16* __restrict__ qkvu, const u16* __restrict__ VT,
    const float* __restrict__ pbT, u16* __restrict__ out)
{
    __shared__ u16 Ks[2][2][64 * 64];   // [group][buf]
    __shared__ u16 Vs[2][2][64 * 64];
    __shared__ float pbl[S_];
    const int tid  = threadIdx.x;
    const int wave = tid >> 6;
    const int grp  = wave >> 2;         // t-half
    const int wq4  = wave & 3;          // q sub-tile
    const int lane = tid & 63;
    const int l31  = lane & 31;
    const int hi   = lane >> 5;
    const int l7   = lane & 7;
    const int xorv = l7 ^ ((l31 >> 3) & 3);   // read-side swizzle key
    const int flat = blockIdx.x + (blockIdx.y << 4) + (blockIdx.z << 8);
    const int work = ((flat & 7) << 6) + (flat >> 3);
    const int s0 = (work & 15) << 7;
    const int h  = (work >> 4) & 15;
    const int b  = work >> 8;
    const size_t base = (size_t)b * S_ * LQ + (size_t)h * DH;
    const u16* q  = qkvu + base;
    const u16* kg = qkvu + base + 1024;
    const u16* vt = VT + (size_t)(b * NH + h) * 64 * S_;
    const float* pbh = pbT + (size_t)h * S_;

    for (int i = tid * 4; i < S_; i += 2048)
        *(float4*)&pbl[i] = *(const float4*)&pbh[i];

    const int qrow = s0 + wq4 * 32 + l31;
    short8 qf[4];
#pragma unroll
    for (int i = 0; i < 4; ++i)
        qf[i] = *(const short8*)&q[(size_t)qrow * LQ + i * 16 + hi * 8];

    const int lr  = lane >> 3;
    const int gA  = (2 * wq4) & 3;
    const int gB  = (2 * wq4 + 1) & 3;
    const u16* kgA = kg + (size_t)(16 * wq4 + lr) * LQ     + ((l7 ^ lr ^ gA) << 3);
    const u16* kgB = kg + (size_t)(16 * wq4 + 8 + lr) * LQ + ((l7 ^ lr ^ gB) << 3);
    const u16* vgA = vt + (size_t)(16 * wq4 + lr) * S_     + ((l7 ^ lr ^ gA) << 3);
    const u16* vgB = vt + (size_t)(16 * wq4 + 8 + lr) * S_ + ((l7 ^ lr ^ gB) << 3);

#define ISSUE(it, bu) do { \
        const size_t tn = ((size_t)(grp) * 16 + (size_t)(it)) << 6; \
        GLDS16(kgA + tn * LQ, &Ks[grp][bu][(16 * wq4) * 64]); \
        GLDS16(kgB + tn * LQ, &Ks[grp][bu][(16 * wq4 + 8) * 64]); \
        GLDS16(vgA + tn,      &Vs[grp][bu][(16 * wq4) * 64]); \
        GLDS16(vgB + tn,      &Vs[grp][bu][(16 * wq4 + 8) * 64]); \
    } while (0)

    f32x16 accO[2] = {};
    ISSUE(0, 0);
    __syncthreads();

#pragma unroll 1
    for (int it = 0; it < 16; ++it) {
        const int ib = it & 1;
        const int nb = ib ^ 1;
        if (it + 1 < 16) ISSUE(it + 1, nb);
        const int t0 = grp * 1024 + (it << 6);
        f32x16 st0 = {}, st1 = {};
        __builtin_amdgcn_s_setprio(1);
#pragma unroll
        for (int i = 0; i < 4; ++i) {
            const int co = ((2 * i + hi) ^ xorv) << 3;
            short8 kf0 = *(const short8*)&Ks[grp][ib][(l31) * 64 + co];
            short8 kf1 = *(const short8*)&Ks[grp][ib][(32 + l31) * 64 + co];
            st0 = __builtin_amdgcn_mfma_f32_32x32x16_bf16(kf0, qf[i], st0, 0, 0, 0);
            st1 = __builtin_amdgcn_mfma_f32_32x32x16_bf16(kf1, qf[i], st1, 0, 0, 0);
        }
        __builtin_amdgcn_s_setprio(0);
        int pk0[8], pk1[8];
#pragma unroll
        for (int g = 0; g < 4; ++g) {
            float4 pbv0 = *(const float4*)&pbl[t0 + 8 * g + 4 * hi];
            float4 pbv1 = *(const float4*)&pbl[t0 + 32 + 8 * g + 4 * hi];
            float a0 = silu_fast(fmaf(st0[4 * g + 0], 0.125f, pbv0.x));
            float a1 = silu_fast(fmaf(st0[4 * g + 1], 0.125f, pbv0.y));
            float a2 = silu_fast(fmaf(st0[4 * g + 2], 0.125f, pbv0.z));
            float a3 = silu_fast(fmaf(st0[4 * g + 3], 0.125f, pbv0.w));
            float b0 = silu_fast(fmaf(st1[4 * g + 0], 0.125f, pbv1.x));
            float b1 = silu_fast(fmaf(st1[4 * g + 1], 0.125f, pbv1.y));
            float b2 = silu_fast(fmaf(st1[4 * g + 2], 0.125f, pbv1.z));
            float b3 = silu_fast(fmaf(st1[4 * g + 3], 0.125f, pbv1.w));
            asm("v_cvt_pk_bf16_f32 %0, %1, %2" : "=v"(pk0[2 * g])     : "v"(a0), "v"(a1));
            asm("v_cvt_pk_bf16_f32 %0, %1, %2" : "=v"(pk0[2 * g + 1]) : "v"(a2), "v"(a3));
            asm("v_cvt_pk_bf16_f32 %0, %1, %2" : "=v"(pk1[2 * g])     : "v"(b0), "v"(b1));
            asm("v_cvt_pk_bf16_f32 %0, %1, %2" : "=v"(pk1[2 * g + 1]) : "v"(b2), "v"(b3));
        }
#pragma unroll
        for (int m = 0; m < 2; ++m) {
            int w0 = pk0[4 * m + 0], w2 = pk0[4 * m + 2];
            int w1 = pk0[4 * m + 1], w3 = pk0[4 * m + 3];
            asm("v_permlane32_swap_b32 %0, %1" : "+v"(w0), "+v"(w2));
            asm("v_permlane32_swap_b32 %0, %1" : "+v"(w1), "+v"(w3));
            int u0 = pk1[4 * m + 0], u2 = pk1[4 * m + 2];
            int u1 = pk1[4 * m + 1], u3 = pk1[4 * m + 3];
            asm("v_permlane32_swap_b32 %0, %1" : "+v"(u0), "+v"(u2));
            asm("v_permlane32_swap_b32 %0, %1" : "+v"(u1), "+v"(u3));
            union { int4v i; short8 s; } pa, pb2;
            pa.i.x  = w0; pa.i.y  = w1; pa.i.z  = w2; pa.i.w  = w3;
            pb2.i.x = u0; pb2.i.y = u1; pb2.i.z = u2; pb2.i.w = u3;
            __builtin_amdgcn_s_setprio(1);
#pragma unroll
            for (int n = 0; n < 2; ++n) {
                short8 vf0 = *(const short8*)&Vs[grp][ib][(32 * n + l31) * 64 +
                    (((2 * m + hi) ^ xorv) << 3)];
                short8 vf1 = *(const short8*)&Vs[grp][ib][(32 * n + l31) * 64 +
                    (((4 + 2 * m + hi) ^ xorv) << 3)];
                accO[n] = __builtin_amdgcn_mfma_f32_32x32x16_bf16(pa.s,  vf0, accO[n], 0, 0, 0);
                accO[n] = __builtin_amdgcn_mfma_f32_32x32x16_bf16(pb2.s, vf1, accO[n], 0, 0, 0);
            }
            __builtin_amdgcn_s_setprio(0);
        }
        __syncthreads();
    }
#undef ISSUE
    float* scr = (float*)&Ks[0][0][0];
    const int sl = wq4 * 64 + lane;
    if (grp == 1) {
#pragma unroll
        for (int n = 0; n < 2; ++n)
#pragma unroll
            for (int r = 0; r < 16; ++r)
                scr[(n * 16 + r) * 256 + sl] = accO[n][r];
    }
    __syncthreads();
    if (grp == 0) {
#pragma unroll
        for (int n = 0; n < 2; ++n)
#pragma unroll
            for (int r = 0; r < 16; ++r)
                accO[n][r] += scr[(n * 16 + r) * 256 + sl];
        const int qb = s0 + wq4 * 32 + 4 * hi;
#pragma unroll
        for (int n = 0; n < 2; ++n)
#pragma unroll
            for (int r = 0; r < 16; ++r) {
                const int qq = qb + (r & 3) + 8 * (r >> 2);
                out[base + (size_t)qq * LQ + 32 * n + l31] = f2bf(accO[n][r]);
            }
    }
}

extern "C" void kernel_launch(void* const* d_in, const int* in_sizes, int n_in,
                              void* d_out, int out_size, void* d_ws, size_t ws_size,
                              hipStream_t stream)
{
    const float* x      = (const float*)d_in[0];
    const float* pb     = (const float*)d_in[2];
    const float* wq     = (const float*)d_in[3];
    const float* bq     = (const float*)d_in[4];
    const float* wk     = (const float*)d_in[5];
    const float* bk     = (const float*)d_in[6];
    const float* wv     = (const float*)d_in[7];
    const float* bv     = (const float*)d_in[8];
    const float* wu     = (const float*)d_in[9];
    const float* bu     = (const float*)d_in[10];
    const float* g_ams  = (const float*)d_in[11];
    const float* w0     = (const float*)d_in[12];
    const float* b0     = (const float*)d_in[13];
    const float* w1     = (const float*)d_in[14];
    const float* b1     = (const float*)d_in[15];
    const float* w2     = (const float*)d_in[16];
    const float* b2     = (const float*)d_in[17];
    const float* g_mffn = (const float*)d_in[18];
    float* OUT = (float*)d_out;
    u16*   VT  = (u16*)d_out;              // VT[b][h][64][2048] (8 MB) — dead after attn
    float* pbT = (float*)((u16*)d_out + 4 * (1u << 20));  // 128KB at +8MB — dead after attn

    const size_t MI = 1024 * 1024;
    u16* WS   = (u16*)d_ws;                // 56 MB total
    u16* wT4  = WS;
    u16* w0T  = WS + 4 * MI;
    u16* w2T  = WS + 5 * MI;
    u16* w1T  = WS + 6 * MI;
    u16* A0   = WS + 8 * MI;
    u16* QKVU = WS + 12 * MI;

    dim3 blk(256);

    transpose_all_kernel<<<dim3(16, 16, 9), blk, 0, stream>>>(
        wq, wk, wv, wu, w0, w2, w1, wT4, w0T, w2T, w1T, pb, pbT);

    rmsnorm_kernel<<<ROWS, blk, 0, stream>>>(x, nullptr, D, g_ams, nullptr, 0, A0, D);
    gemm128<<<dim3(32, 32), blk, 0, stream>>>(A0, wT4, bq, bk, bv, bu,
                                              QKVU, LQ, 0b1000, VT, 2);
    attn_mfma<<<dim3(16, 16, 2), dim3(512), 0, stream>>>(QKVU, VT, pbT, QKVU);
    rmsnorm_kernel<<<ROWS, blk, 0, stream>>>(nullptr, QKVU, LQ, g_ams, QKVU + 3072, LQ, A0, D);
    gemm64<<<dim3(16, 64), blk, 0, stream>>>(A0, D, w0T, b0, x, OUT, D);
    rmsnorm_kernel<<<ROWS, blk, 0, stream>>>(OUT, nullptr, D, g_mffn, nullptr, 0, A0, D);
    gemm_w1_swiglu<<<dim3(16, 64), blk, 0, stream>>>(A0, w1T, b1, QKVU + 2048);
    gemm64<<<dim3(16, 64), blk, 0, stream>>>(QKVU + 2048, LQ, w2T, b2, OUT, OUT, D);
    (void)ws_size; (void)in_sizes; (void)n_in; (void)out_size;
}